// Round 1
// baseline (11206.779 us; speedup 1.0000x reference)
//
#include <hip/hip_runtime.h>

#define NPTS  288
#define DIMS  2048
#define KC    6
#define N_IT  25
#define BLK   1024

__global__ __launch_bounds__(BLK, 4) void kmeans_kernel(const float* __restrict__ x,
                                                        float* __restrict__ out,
                                                        int nbatch) {
  const int b = blockIdx.x;
  if (b >= nbatch) return;
  const int t    = threadIdx.x;
  const int wv   = t >> 6;
  const int lane = t & 63;
  const float* __restrict__ Mb = x + (size_t)b * ((size_t)DIMS * NPTS);  // M[c][j]
  float* __restrict__ gcent = out + (size_t)b * (DIMS * KC);             // scratch: centers [KC][DIMS]

  __shared__ float part[3][KC][NPTS];   // partial dot products per c-range group
  __shared__ float csqh[KC];            // 0.5 * |center|^2
  __shared__ __attribute__((aligned(16))) int assign_s[NPTS];
  __shared__ int cnt_i[KC];

  // ---- init: centers0 = first KC points ----
  // gcent[k*DIMS + c] = M[c][k]
#pragma unroll
  for (int i = 0; i < 12; ++i) {       // 12*1024 == KC*DIMS
    int e = t + BLK * i;
    int k = e / DIMS;
    int c = e - k * DIMS;
    gcent[e] = Mb[(size_t)c * NPTS + k];
  }
  __syncthreads();

  for (int it = 0; it < N_IT; ++it) {
    if (t < KC) cnt_i[t] = 0;

    // ---- csq/2: waves 0..5, one center each ----
    if (wv < KC) {
      float s = 0.f;
#pragma unroll 8
      for (int i = 0; i < DIMS / 64; ++i) {
        float v = gcent[wv * DIMS + lane + 64 * i];
        s += v * v;
      }
#pragma unroll
      for (int off = 32; off; off >>= 1) s += __shfl_xor(s, off, 64);
      if (lane == 0) csqh[wv] = 0.5f * s;
    }

    // ---- dots: 3 groups x 5 waves; lanes <-> points; partial over c-range ----
    if (wv < 15) {
      const int g = wv / 5;            // 0..2
      const int q = t - g * 320;       // 0..319; point index if < NPTS
      if (q < NPTS) {
        const int c0 = (g == 0) ? 0   : (g == 1 ? 684  : 1368);
        const int c1 = (g == 0) ? 684 : (g == 1 ? 1368 : 2048);
        float acc[KC];
#pragma unroll
        for (int k = 0; k < KC; ++k) acc[k] = 0.f;
        const float* __restrict__ pb = Mb + q;
        for (int c = c0; c < c1; c += 4) {
          const float p0 = pb[(size_t)(c + 0) * NPTS];   // coalesced across lanes
          const float p1 = pb[(size_t)(c + 1) * NPTS];
          const float p2 = pb[(size_t)(c + 2) * NPTS];
          const float p3 = pb[(size_t)(c + 3) * NPTS];
#pragma unroll
          for (int k = 0; k < KC; ++k) {
            const float4 cv = *(const float4*)(gcent + k * DIMS + c);  // wave-uniform
            acc[k] += p0 * cv.x + p1 * cv.y + p2 * cv.z + p3 * cv.w;
          }
        }
#pragma unroll
        for (int k = 0; k < KC; ++k) part[g][k][q] = acc[k];
      }
    }
    __syncthreads();  // bar1: partials + csqh ready

    // ---- reduce + argmin + counts ----
    int myA = -1;
    if (t < NPTS) {
      float best = 0.f;
      int   bi   = 0;
#pragma unroll
      for (int k = 0; k < KC; ++k) {
        const float S  = part[0][k][t] + part[1][k][t] + part[2][k][t];
        const float sc = csqh[k] - S;          // argmin_k(d) == argmin_k(csq/2 - S)
        if (k == 0 || sc < best) { best = sc; bi = k; }
      }
      assign_s[t] = bi;
      myA = bi;
    }
    if (t < 320) {   // waves 0..4 (uniform per-wave predicate)
#pragma unroll
      for (int k = 0; k < KC; ++k) {
        unsigned long long m = __ballot(myA == k);
        if (lane == 0) atomicAdd(&cnt_i[k], (int)__popcll(m));  // int atomics: deterministic
      }
    }
    __syncthreads();  // bar2: assign + counts ready

    // ---- sums + center update: thread <-> dim pair (c0 = t, c1 = t+1024) ----
    {
      const int c0 = t;
      const int c1 = t + BLK;
      float s0a=0,s0b=0,s1a=0,s1b=0,s2a=0,s2b=0,s3a=0,s3b=0,s4a=0,s4b=0,s5a=0,s5b=0;
      const float* __restrict__ r0 = Mb + (size_t)c0 * NPTS;
      const float* __restrict__ r1 = Mb + (size_t)c1 * NPTS;
      auto step = [&](int a, float pv, float qv) {
        const int as = __builtin_amdgcn_readfirstlane(a);  // assign[j] is wave-uniform
        if      (as == 0) { s0a += pv; s0b += qv; }
        else if (as == 1) { s1a += pv; s1b += qv; }
        else if (as == 2) { s2a += pv; s2b += qv; }
        else if (as == 3) { s3a += pv; s3b += qv; }
        else if (as == 4) { s4a += pv; s4b += qv; }
        else              { s5a += pv; s5b += qv; }
      };
      for (int j = 0; j < NPTS; j += 4) {
        const float4 p  = *(const float4*)(r0 + j);
        const float4 qv = *(const float4*)(r1 + j);
        const int4   av = *(const int4*)(assign_s + j);    // uniform LDS b128
        step(av.x, p.x, qv.x);
        step(av.y, p.y, qv.y);
        step(av.z, p.z, qv.z);
        step(av.w, p.w, qv.w);
      }
#define FINK(k, sa, sb) {                                        \
        const int   cn = cnt_i[k];                               \
        const float fc = (float)cn;                              \
        const float o0 = gcent[(k) * DIMS + c0];                 \
        const float o1 = gcent[(k) * DIMS + c1];                 \
        gcent[(k) * DIMS + c0] = (cn > 0) ? (sa / fc) : o0;      \
        gcent[(k) * DIMS + c1] = (cn > 0) ? (sb / fc) : o1;      \
      }
      FINK(0, s0a, s0b) FINK(1, s1a, s1b) FINK(2, s2a, s2b)
      FINK(3, s3a, s3b) FINK(4, s4a, s4b) FINK(5, s5a, s5b)
#undef FINK
    }
    __syncthreads();  // bar3: new centers visible
  }

  // ---- final in-place transpose: [KC][DIMS] -> out layout [DIMS][KC] ----
  float v[12];
#pragma unroll
  for (int i = 0; i < 12; ++i) {
    const int o = t + BLK * i;
    const int c = o / KC;
    const int k = o - c * KC;
    v[i] = gcent[k * DIMS + c];
  }
  __syncthreads();  // __syncthreads drains vmcnt(0): all reads complete before any write
#pragma unroll
  for (int i = 0; i < 12; ++i) gcent[t + BLK * i] = v[i];
}

extern "C" void kernel_launch(void* const* d_in, const int* in_sizes, int n_in,
                              void* d_out, int out_size, void* d_ws, size_t ws_size,
                              hipStream_t stream) {
  const float* x  = (const float*)d_in[0];
  float* out      = (float*)d_out;
  const int nbatch = in_sizes[0] / (DIMS * NPTS);   // 64
  hipLaunchKernelGGL(kmeans_kernel, dim3(nbatch), dim3(BLK), 0, stream, x, out, nbatch);
}

// Round 3
// 3823.218 us; speedup vs baseline: 2.9312x; 2.9312x over previous
//
#include <hip/hip_runtime.h>

#define NPTS 288
#define DIMS 2048
#define KC   6
#define N_IT 25
#define BLK  1024
#define NSL  4              // dim-slices per batch (1 block each)
#define SLD  (DIMS / NSL)   // 512 dims per slice

// ---------------- K0: init centers = first KC points ----------------
// cent[b][k][c] = M[c][k]
__global__ __launch_bounds__(BLK) void k_init(const float* __restrict__ x,
                                              float* __restrict__ cent) {
  const int b = blockIdx.x >> 2, s = blockIdx.x & 3;
  const int t = threadIdx.x;
  const float* __restrict__ Mb = x + (size_t)b * (DIMS * NPTS);
#pragma unroll
  for (int i = 0; i < 3; ++i) {
    const int e  = t + BLK * i;      // 0..3071 = KC*SLD
    const int k  = e >> 9;           // e / SLD
    const int cl = e & (SLD - 1);
    const int c  = s * SLD + cl;
    cent[((size_t)b * KC + k) * DIMS + c] = Mb[(size_t)c * NPTS + k];
  }
}

// ---------------- K1: partial dots + partial csq over one dim slice ----------------
__global__ __launch_bounds__(BLK) void k_dots(const float* __restrict__ x,
                                              const float* __restrict__ cent,
                                              float* __restrict__ part,
                                              float* __restrict__ csqp) {
  const int b = blockIdx.x >> 2, s = blockIdx.x & 3;
  const int t = threadIdx.x, wv = t >> 6, lane = t & 63;
  const float* __restrict__ Mb = x + (size_t)b * (DIMS * NPTS);
  const float* __restrict__ cb = cent + (size_t)b * (KC * DIMS);

  __shared__ __attribute__((aligned(16))) float cs[KC][SLD];   // 12 KB center slice
  __shared__ float part_l[3][KC][NPTS];                        // 20.25 KB group partials
#pragma unroll
  for (int i = 0; i < 3; ++i) {
    const int e = t + BLK * i;
    const int k = e >> 9, cl = e & (SLD - 1);
    cs[k][cl] = cb[(size_t)k * DIMS + s * SLD + cl];
  }
  __syncthreads();

  if (wv < 15) {
    // 3 dim-groups x 5 waves; lanes <-> points; DISJOINT LDS slots per group
    const int g = wv / 5;
    const int q = t - g * 320;
    if (q < NPTS) {
      const int c0 = (g == 0) ? 0   : (g == 1 ? 172 : 344);
      const int c1 = (g == 0) ? 172 : (g == 1 ? 344 : 512);
      float acc[KC];
#pragma unroll
      for (int k = 0; k < KC; ++k) acc[k] = 0.f;
      const float* __restrict__ pb = Mb + (size_t)(s * SLD) * NPTS + q;
#pragma unroll 2
      for (int c = c0; c < c1; c += 4) {
        const float p0 = pb[(size_t)(c + 0) * NPTS];   // coalesced across lanes
        const float p1 = pb[(size_t)(c + 1) * NPTS];
        const float p2 = pb[(size_t)(c + 2) * NPTS];
        const float p3 = pb[(size_t)(c + 3) * NPTS];
#pragma unroll
        for (int k = 0; k < KC; ++k) {
          const float4 cv = *(const float4*)&cs[k][c];  // wave-uniform LDS broadcast
          acc[k] += p0 * cv.x + p1 * cv.y + p2 * cv.z + p3 * cv.w;
        }
      }
#pragma unroll
      for (int k = 0; k < KC; ++k) part_l[g][k][q] = acc[k];
    }
  } else {
    // wave 15: csq partial over the slice
    float a[KC];
#pragma unroll
    for (int k = 0; k < KC; ++k) a[k] = 0.f;
#pragma unroll
    for (int i = 0; i < SLD / 64; ++i) {
#pragma unroll
      for (int k = 0; k < KC; ++k) {
        const float v = cs[k][lane + 64 * i];
        a[k] += v * v;
      }
    }
#pragma unroll
    for (int k = 0; k < KC; ++k) {
#pragma unroll
      for (int off = 32; off; off >>= 1) a[k] += __shfl_xor(a[k], off, 64);
    }
    if (lane == 0) {
#pragma unroll
      for (int k = 0; k < KC; ++k)
        csqp[(size_t)(b * NSL + s) * KC + k] = a[k];
    }
  }
  __syncthreads();   // group partials ready

  // reduce the 3 dim-groups in fixed order -> one global partial per (slice,k,q)
  if (t < NPTS) {
#pragma unroll
    for (int k = 0; k < KC; ++k)
      part[((size_t)(b * NSL + s) * KC + k) * NPTS + t] =
          part_l[0][k][t] + part_l[1][k][t] + part_l[2][k][t];
  }
}

// ---------------- K2: redundant argmin + per-slice sums + center update ----------------
__global__ __launch_bounds__(BLK) void k_assign_sums(const float* __restrict__ x,
                                                     float* __restrict__ cent,
                                                     const float* __restrict__ part,
                                                     const float* __restrict__ csqp) {
  const int b = blockIdx.x >> 2, s = blockIdx.x & 3;
  const int t = threadIdx.x, lane = t & 63;
  const float* __restrict__ Mb = x + (size_t)b * (DIMS * NPTS);
  float* __restrict__ cb = cent + (size_t)b * (KC * DIMS);

  __shared__ float csqh[KC];
  __shared__ int cnt_i[KC];
  __shared__ __attribute__((aligned(16))) int assign_s[NPTS];
  __shared__ float pool[KC][SLD][2];   // 24 KB

  if (t < KC) {
    const float* pc = csqp + (size_t)b * NSL * KC + t;
    csqh[t] = 0.5f * (pc[0] + pc[KC] + pc[2 * KC] + pc[3 * KC]);  // fixed order: deterministic
    cnt_i[t] = 0;
  }
  __syncthreads();

  int myA = -1;
  if (t < NPTS) {
    const float* pp = part + (size_t)b * NSL * KC * NPTS + t;
    float best = 0.f;
    int bi = 0;
#pragma unroll
    for (int k = 0; k < KC; ++k) {
      const float S = pp[(size_t)k * NPTS] + pp[(size_t)(KC + k) * NPTS] +
                      pp[(size_t)(2 * KC + k) * NPTS] + pp[(size_t)(3 * KC + k) * NPTS];
      const float sc = csqh[k] - S;     // argmin_k(d) == argmin_k(csq/2 - S)
      if (k == 0 || sc < best) { best = sc; bi = k; }
    }
    assign_s[t] = bi;
    myA = bi;
  }
  if (t < 320) {   // waves 0..4, uniform predicate
#pragma unroll
    for (int k = 0; k < KC; ++k) {
      unsigned long long m = __ballot(myA == k);
      if (lane == 0) atomicAdd(&cnt_i[k], (int)__popcll(m));  // int atomics: deterministic
    }
  }
  __syncthreads();   // assign + counts ready

  // sums: thread <-> (dim, point-half); wave-uniform j walk
  {
    const int half = t >> 9;            // uniform within each wave (512 is wave-aligned)
    const int cl   = t & (SLD - 1);
    const int c    = s * SLD + cl;
    float s0 = 0, s1 = 0, s2 = 0, s3 = 0, s4 = 0, s5 = 0;
    const float* __restrict__ r0 = Mb + (size_t)c * NPTS + half * 144;
    const int jbase = half * 144;
    auto step = [&](int a, float pv) {
      const int as = __builtin_amdgcn_readfirstlane(a);   // assign[j] wave-uniform
      if      (as == 0) s0 += pv;
      else if (as == 1) s1 += pv;
      else if (as == 2) s2 += pv;
      else if (as == 3) s3 += pv;
      else if (as == 4) s4 += pv;
      else              s5 += pv;
    };
    for (int j = 0; j < 144; j += 4) {
      const float4 p = *(const float4*)(r0 + j);
      const int4  av = *(const int4*)(assign_s + jbase + j);
      step(av.x, p.x); step(av.y, p.y); step(av.z, p.z); step(av.w, p.w);
    }
    pool[0][cl][half] = s0; pool[1][cl][half] = s1; pool[2][cl][half] = s2;
    pool[3][cl][half] = s3; pool[4][cl][half] = s4; pool[5][cl][half] = s5;
  }
  __syncthreads();

  if (t < SLD) {
    const int c = s * SLD + t;
#pragma unroll
    for (int k = 0; k < KC; ++k) {
      const float sum = pool[k][t][0] + pool[k][t][1];
      const int cn = cnt_i[k];
      const float oldv = cb[(size_t)k * DIMS + c];
      cb[(size_t)k * DIMS + c] = (cn > 0) ? (sum / (float)cn) : oldv;
    }
  }
}

// ---------------- K3a/K3b: transpose [KC][DIMS] -> [DIMS][KC] via ws staging ----------------
__global__ __launch_bounds__(BLK) void k_stage(const float* __restrict__ cent,
                                               float* __restrict__ stage) {
  const int b = blockIdx.x >> 2, s = blockIdx.x & 3;
  const int t = threadIdx.x;
#pragma unroll
  for (int i = 0; i < 3; ++i) {
    const int e = t + BLK * i;          // 0..3071
    const int k = e >> 9, cl = e & (SLD - 1);
    stage[(size_t)blockIdx.x * 3072 + e] =
        cent[((size_t)b * KC + k) * DIMS + s * SLD + cl];
  }
}

__global__ __launch_bounds__(BLK) void k_out(const float* __restrict__ stage,
                                             float* __restrict__ out) {
  const int b = blockIdx.x >> 2, s = blockIdx.x & 3;
  const int t = threadIdx.x;
#pragma unroll
  for (int i = 0; i < 3; ++i) {
    const int e  = t + BLK * i;         // 0..3071
    const int cl = e / KC;
    const int k  = e - cl * KC;
    const int c  = s * SLD + cl;
    out[((size_t)b * DIMS + c) * KC + k] =
        stage[(size_t)blockIdx.x * 3072 + k * SLD + cl];
  }
}

extern "C" void kernel_launch(void* const* d_in, const int* in_sizes, int n_in,
                              void* d_out, int out_size, void* d_ws, size_t ws_size,
                              hipStream_t stream) {
  const float* x = (const float*)d_in[0];
  float* out     = (float*)d_out;
  const int nb   = in_sizes[0] / (DIMS * NPTS);   // 64

  // centers live in d_out during iterations; ws holds partials (+ reused as transpose staging)
  float* cent = out;
  float* part = (float*)d_ws;                               // nb*NSL*KC*NPTS floats = 1.7 MB
  float* csqp = part + (size_t)nb * NSL * KC * NPTS;        // nb*NSL*KC floats
  float* stage = part;                                      // reuse after last K2

  const dim3 grid(nb * NSL), blk(BLK);
  hipLaunchKernelGGL(k_init, grid, blk, 0, stream, x, cent);
  for (int it = 0; it < N_IT; ++it) {
    hipLaunchKernelGGL(k_dots,        grid, blk, 0, stream, x, cent, part, csqp);
    hipLaunchKernelGGL(k_assign_sums, grid, blk, 0, stream, x, cent, part, csqp);
  }
  hipLaunchKernelGGL(k_stage, grid, blk, 0, stream, cent, stage);
  hipLaunchKernelGGL(k_out,   grid, blk, 0, stream, stage, out);
}

// Round 4
// 1619.757 us; speedup vs baseline: 6.9188x; 2.3604x over previous
//
#include <hip/hip_runtime.h>

#define NPTS 288
#define DIMS 2048
#define KC   6
#define N_IT 25
#define BLK  1024
#define NSL  4              // dim-slices per batch (1 block each)
#define SLD  (DIMS / NSL)   // 512 dims per slice

// ---------------- K0: init centers = first KC points ----------------
__global__ __launch_bounds__(BLK) void k_init(const float* __restrict__ x,
                                              float* __restrict__ cent) {
  const int b = blockIdx.x >> 2, s = blockIdx.x & 3;
  const int t = threadIdx.x;
  const float* __restrict__ Mb = x + (size_t)b * (DIMS * NPTS);
#pragma unroll
  for (int i = 0; i < 3; ++i) {
    const int e  = t + BLK * i;      // 0..3071 = KC*SLD
    const int k  = e >> 9;
    const int cl = e & (SLD - 1);
    const int c  = s * SLD + cl;
    cent[((size_t)b * KC + k) * DIMS + c] = Mb[(size_t)c * NPTS + k];
  }
}

// ---------------- K1: dots for the INITIAL centers (prologue only) ----------------
__global__ __launch_bounds__(BLK) void k_dots(const float* __restrict__ x,
                                              const float* __restrict__ cent,
                                              float* __restrict__ part,
                                              float* __restrict__ csqp) {
  const int b = blockIdx.x >> 2, s = blockIdx.x & 3;
  const int t = threadIdx.x, wv = t >> 6, lane = t & 63;
  const float* __restrict__ Mb = x + (size_t)b * (DIMS * NPTS);
  const float* __restrict__ cb = cent + (size_t)b * (KC * DIMS);

  __shared__ __attribute__((aligned(16))) float cs[KC][SLD];
  __shared__ float part_l[3][KC][NPTS];
#pragma unroll
  for (int i = 0; i < 3; ++i) {
    const int e = t + BLK * i;
    const int k = e >> 9, cl = e & (SLD - 1);
    cs[k][cl] = cb[(size_t)k * DIMS + s * SLD + cl];
  }
  __syncthreads();

  if (wv < 15) {
    const int g = wv / 5;
    const int q = t - g * 320;
    if (q < NPTS) {
      const int c0 = (g == 0) ? 0   : (g == 1 ? 172 : 344);
      const int c1 = (g == 0) ? 172 : (g == 1 ? 344 : 512);
      float acc[KC];
#pragma unroll
      for (int k = 0; k < KC; ++k) acc[k] = 0.f;
      const float* __restrict__ pb = Mb + (size_t)(s * SLD) * NPTS + q;
#pragma unroll 2
      for (int c = c0; c < c1; c += 4) {
        const float p0 = pb[(size_t)(c + 0) * NPTS];
        const float p1 = pb[(size_t)(c + 1) * NPTS];
        const float p2 = pb[(size_t)(c + 2) * NPTS];
        const float p3 = pb[(size_t)(c + 3) * NPTS];
#pragma unroll
        for (int k = 0; k < KC; ++k) {
          const float4 cv = *(const float4*)&cs[k][c];
          acc[k] += p0 * cv.x + p1 * cv.y + p2 * cv.z + p3 * cv.w;
        }
      }
#pragma unroll
      for (int k = 0; k < KC; ++k) part_l[g][k][q] = acc[k];
    }
  } else {
    float a[KC];
#pragma unroll
    for (int k = 0; k < KC; ++k) a[k] = 0.f;
#pragma unroll
    for (int i = 0; i < SLD / 64; ++i) {
#pragma unroll
      for (int k = 0; k < KC; ++k) {
        const float v = cs[k][lane + 64 * i];
        a[k] += v * v;
      }
    }
#pragma unroll
    for (int k = 0; k < KC; ++k) {
#pragma unroll
      for (int off = 32; off; off >>= 1) a[k] += __shfl_xor(a[k], off, 64);
    }
    if (lane == 0) {
#pragma unroll
      for (int k = 0; k < KC; ++k)
        csqp[(size_t)(b * NSL + s) * KC + k] = a[k];
    }
  }
  __syncthreads();

  if (t < NPTS) {
#pragma unroll
    for (int k = 0; k < KC; ++k)
      part[((size_t)(b * NSL + s) * KC + k) * NPTS + t] =
          part_l[0][k][t] + part_l[1][k][t] + part_l[2][k][t];
  }
}

// ---------------- K2: fused iteration: argmin -> staged sums -> update -> dots ----------------
__global__ __launch_bounds__(BLK) void k_iter(const float* __restrict__ x,
                                              float* __restrict__ cent,
                                              float* __restrict__ part,
                                              float* __restrict__ csqp,
                                              int do_dots) {
  const int b = blockIdx.x >> 2, s = blockIdx.x & 3;
  const int t = threadIdx.x, wv = t >> 6, lane = t & 63;
  const float* __restrict__ Mb = x + (size_t)b * (DIMS * NPTS);
  float* __restrict__ cb = cent + (size_t)b * (KC * DIMS);

  __shared__ __attribute__((aligned(16))) float cs[KC][SLD];        // 12 KB
  __shared__ float tile[64 * 145];                                  // 37.1 KB, pad 145
  __shared__ __attribute__((aligned(16))) char upool[26112];        // pool / part_l union
  __shared__ __attribute__((aligned(16))) int assign_s[NPTS];
  __shared__ float csqh[KC];
  __shared__ int cnt_i[KC];

  float (*pool)[64][17]     = (float (*)[64][17])(void*)upool;      // [KC][64][17]
  float (*part_l)[KC][NPTS] = (float (*)[KC][NPTS])(void*)upool;    // [3][KC][NPTS]

  // old centers slice -> LDS (needed for empty-cluster fallback + dots base)
#pragma unroll
  for (int i = 0; i < 3; ++i) {
    const int e = t + BLK * i;
    const int k = e >> 9, cl = e & (SLD - 1);
    cs[k][cl] = cb[(size_t)k * DIMS + s * SLD + cl];
  }

  // ---- phase 0: argmin (redundant per slice-block; fixed-order = deterministic) ----
  if (t < KC) {
    const float* pc = csqp + (size_t)b * NSL * KC + t;
    csqh[t] = 0.5f * (pc[0] + pc[KC] + pc[2 * KC] + pc[3 * KC]);
    cnt_i[t] = 0;
  }
  __syncthreads();

  int myA = -1;
  if (t < NPTS) {
    const float* pp = part + (size_t)b * NSL * KC * NPTS + t;
    float best = 0.f;
    int bi = 0;
#pragma unroll
    for (int k = 0; k < KC; ++k) {
      const float S = pp[(size_t)k * NPTS] + pp[(size_t)(KC + k) * NPTS] +
                      pp[(size_t)(2 * KC + k) * NPTS] + pp[(size_t)(3 * KC + k) * NPTS];
      const float sc = csqh[k] - S;     // argmin_k(d) == argmin_k(csq/2 - S)
      if (k == 0 || sc < best) { best = sc; bi = k; }
    }
    assign_s[t] = bi;
    myA = bi;
  }
  if (t < 320) {
#pragma unroll
    for (int k = 0; k < KC; ++k) {
      unsigned long long m = __ballot(myA == k);
      if (lane == 0) atomicAdd(&cnt_i[k], (int)__popcll(m));
    }
  }
  __syncthreads();   // assign + counts ready

  // hoist this wave's 18 point-assignments into SGPRs (wave-uniform addresses)
  int aj[2][9];
#pragma unroll
  for (int h = 0; h < 2; ++h)
#pragma unroll
    for (int r = 0; r < 9; ++r)
      aj[h][r] = __builtin_amdgcn_readfirstlane(assign_s[h * 144 + wv * 9 + r]);

  // ---- sums sweep: 8 dim-tiles x 2 point-halves; wave = 64 lanes <-> 64 dims ----
  for (int dt = 0; dt < 8; ++dt) {
    float s0 = 0, s1 = 0, s2 = 0, s3 = 0, s4 = 0, s5 = 0;
#pragma unroll
    for (int h = 0; h < 2; ++h) {
      // stage [64][144] coalesced
#pragma unroll
      for (int i = 0; i < 9; ++i) {
        const int e = t + BLK * i;           // 0..9215
        const int d = e / 144, j = e - d * 144;
        tile[d * 145 + j] = Mb[(size_t)(s * SLD + dt * 64 + d) * NPTS + h * 144 + j];
      }
      __syncthreads();
      const int base = lane * 145 + wv * 9;  // lane <-> dim, wave <-> point group
#pragma unroll
      for (int r = 0; r < 9; ++r) {
        const float p = tile[base + r];
        const int a = aj[h][r];              // SGPR -> scalar branch, body = 1 v_add
        if      (a == 0) s0 += p;
        else if (a == 1) s1 += p;
        else if (a == 2) s2 += p;
        else if (a == 3) s3 += p;
        else if (a == 4) s4 += p;
        else             s5 += p;
      }
      __syncthreads();                       // before next stage overwrites tile
    }
    // flush per-wave partials, reduce across 16 waves, update center dims
    pool[0][lane][wv] = s0; pool[1][lane][wv] = s1; pool[2][lane][wv] = s2;
    pool[3][lane][wv] = s3; pool[4][lane][wv] = s4; pool[5][lane][wv] = s5;
    __syncthreads();
    if (t < KC * 64) {
      const int k = t >> 6, d = t & 63;
      float sum = 0.f;
#pragma unroll
      for (int w = 0; w < 16; ++w) sum += pool[k][d][w];   // fixed order
      const int cn = cnt_i[k];
      const int cl = dt * 64 + d;
      cs[k][cl] = (cn > 0) ? (sum / (float)cn) : cs[k][cl];
    }
    __syncthreads();
  }

  // store new centers (next dispatch + final output read them)
#pragma unroll
  for (int i = 0; i < 3; ++i) {
    const int e = t + BLK * i;
    const int k = e >> 9, cl = e & (SLD - 1);
    cb[(size_t)k * DIMS + s * SLD + cl] = cs[k][cl];
  }

  // ---- dots phase for the NEW centers (skipped on last iteration) ----
  if (do_dots) {
    if (wv < 15) {
      const int g = wv / 5;
      const int q = t - g * 320;
      if (q < NPTS) {
        const int c0 = (g == 0) ? 0   : (g == 1 ? 172 : 344);
        const int c1 = (g == 0) ? 172 : (g == 1 ? 344 : 512);
        float acc[KC];
#pragma unroll
        for (int k = 0; k < KC; ++k) acc[k] = 0.f;
        const float* __restrict__ pb = Mb + (size_t)(s * SLD) * NPTS + q;
#pragma unroll 2
        for (int c = c0; c < c1; c += 4) {
          const float p0 = pb[(size_t)(c + 0) * NPTS];
          const float p1 = pb[(size_t)(c + 1) * NPTS];
          const float p2 = pb[(size_t)(c + 2) * NPTS];
          const float p3 = pb[(size_t)(c + 3) * NPTS];
#pragma unroll
          for (int k = 0; k < KC; ++k) {
            const float4 cv = *(const float4*)&cs[k][c];
            acc[k] += p0 * cv.x + p1 * cv.y + p2 * cv.z + p3 * cv.w;
          }
        }
#pragma unroll
        for (int k = 0; k < KC; ++k) part_l[g][k][q] = acc[k];
      }
    } else {
      float a[KC];
#pragma unroll
      for (int k = 0; k < KC; ++k) a[k] = 0.f;
#pragma unroll
      for (int i = 0; i < SLD / 64; ++i) {
#pragma unroll
        for (int k = 0; k < KC; ++k) {
          const float v = cs[k][lane + 64 * i];
          a[k] += v * v;
        }
      }
#pragma unroll
      for (int k = 0; k < KC; ++k) {
#pragma unroll
        for (int off = 32; off; off >>= 1) a[k] += __shfl_xor(a[k], off, 64);
      }
      if (lane == 0) {
#pragma unroll
        for (int k = 0; k < KC; ++k)
          csqp[(size_t)(b * NSL + s) * KC + k] = a[k];
      }
    }
    __syncthreads();

    if (t < NPTS) {
#pragma unroll
      for (int k = 0; k < KC; ++k)
        part[((size_t)(b * NSL + s) * KC + k) * NPTS + t] =
            part_l[0][k][t] + part_l[1][k][t] + part_l[2][k][t];
    }
  }
}

// ---------------- K3a/K3b: transpose [KC][DIMS] -> [DIMS][KC] via ws staging ----------------
__global__ __launch_bounds__(BLK) void k_stage(const float* __restrict__ cent,
                                               float* __restrict__ stage) {
  const int b = blockIdx.x >> 2, s = blockIdx.x & 3;
  const int t = threadIdx.x;
#pragma unroll
  for (int i = 0; i < 3; ++i) {
    const int e = t + BLK * i;
    const int k = e >> 9, cl = e & (SLD - 1);
    stage[(size_t)blockIdx.x * 3072 + e] =
        cent[((size_t)b * KC + k) * DIMS + s * SLD + cl];
  }
}

__global__ __launch_bounds__(BLK) void k_out(const float* __restrict__ stage,
                                             float* __restrict__ out) {
  const int b = blockIdx.x >> 2, s = blockIdx.x & 3;
  const int t = threadIdx.x;
#pragma unroll
  for (int i = 0; i < 3; ++i) {
    const int e  = t + BLK * i;
    const int cl = e / KC;
    const int k  = e - cl * KC;
    const int c  = s * SLD + cl;
    out[((size_t)b * DIMS + c) * KC + k] =
        stage[(size_t)blockIdx.x * 3072 + k * SLD + cl];
  }
}

extern "C" void kernel_launch(void* const* d_in, const int* in_sizes, int n_in,
                              void* d_out, int out_size, void* d_ws, size_t ws_size,
                              hipStream_t stream) {
  const float* x = (const float*)d_in[0];
  float* out     = (float*)d_out;
  const int nb   = in_sizes[0] / (DIMS * NPTS);   // 64

  float* cent  = out;                                       // centers live in d_out
  float* part  = (float*)d_ws;                              // nb*NSL*KC*NPTS floats
  float* csqp  = part + (size_t)nb * NSL * KC * NPTS;
  float* stage = part;                                      // reuse after last k_iter

  const dim3 grid(nb * NSL), blk(BLK);
  hipLaunchKernelGGL(k_init, grid, blk, 0, stream, x, cent);
  hipLaunchKernelGGL(k_dots, grid, blk, 0, stream, x, cent, part, csqp);
  for (int it = 0; it < N_IT; ++it) {
    hipLaunchKernelGGL(k_iter, grid, blk, 0, stream, x, cent, part, csqp,
                       (it < N_IT - 1) ? 1 : 0);
  }
  hipLaunchKernelGGL(k_stage, grid, blk, 0, stream, cent, stage);
  hipLaunchKernelGGL(k_out,   grid, blk, 0, stream, stage, out);
}